// Round 3
// baseline (137.062 us; speedup 1.0000x reference)
//
#include <hip/hip_runtime.h>
#include <cmath>

#define NB 8
#define DIM 4096
#define NHQ 32
#define NHKV 8
#define NDH 128
#define MAXSEQ 4096
#define STARTPOS 4095
#define QKV_COLS 6144   // 4096 q + 1024 k + 1024 v
#define RCHUNK 64       // rows per split-K chunk
#define NRC 64          // 4096 / 64
#define SCALE 0.08838834764831845f  // 1/sqrt(128)
#define NCHUNK 32       // attn chunks
#define CPOS 128        // positions per attn chunk

#define DOT4(k, qq) ((k).x*(qq).x + (k).y*(qq).y + (k).z*(qq).z + (k).w*(qq).w)

// ---------------------------------------------------------------------------
// Kernel 1: QKV projection partials.  grid = 12 col-tiles * 64 row-chunks.
__global__ __launch_bounds__(256) void qkv_partial_k(
    const float* __restrict__ x, const float* __restrict__ wq,
    const float* __restrict__ wk, const float* __restrict__ wv,
    float* __restrict__ part) {
  int bid = blockIdx.x;
  int ct = bid % 12, rc = bid / 12;
  int tid = threadIdx.x;
  const float* W; int ldw; int colbase;
  int gcolbase = ct * 512;
  if (ct < 8)       { W = wq; ldw = NHQ * NDH;  colbase = gcolbase; }
  else if (ct < 10) { W = wk; ldw = NHKV * NDH; colbase = gcolbase - 4096; }
  else              { W = wv; ldw = NHKV * NDH; colbase = gcolbase - 5120; }

  __shared__ __align__(16) float xs[RCHUNK][8];
  int rbase = rc * RCHUNK;
  for (int i = tid; i < RCHUNK * 8; i += 256) {
    int b = i >> 6, r = i & 63;
    xs[r][b] = x[b * DIM + rbase + r];
  }
  __syncthreads();

  int col = colbase + tid * 2;
  const float* wp = W + (size_t)rbase * ldw + col;
  float2 acc[8];
#pragma unroll
  for (int b = 0; b < 8; b++) { acc[b].x = 0.f; acc[b].y = 0.f; }

#pragma unroll 8
  for (int r = 0; r < RCHUNK; r++) {
    float2 w2 = *(const float2*)wp; wp += ldw;
    float4 xa = *(const float4*)&xs[r][0];
    float4 xb = *(const float4*)&xs[r][4];
    acc[0].x += xa.x * w2.x; acc[0].y += xa.x * w2.y;
    acc[1].x += xa.y * w2.x; acc[1].y += xa.y * w2.y;
    acc[2].x += xa.z * w2.x; acc[2].y += xa.z * w2.y;
    acc[3].x += xa.w * w2.x; acc[3].y += xa.w * w2.y;
    acc[4].x += xb.x * w2.x; acc[4].y += xb.x * w2.y;
    acc[5].x += xb.y * w2.x; acc[5].y += xb.y * w2.y;
    acc[6].x += xb.z * w2.x; acc[6].y += xb.z * w2.y;
    acc[7].x += xb.w * w2.x; acc[7].y += xb.w * w2.y;
  }
  int gcol = gcolbase + tid * 2;
#pragma unroll
  for (int b = 0; b < 8; b++)
    *(float2*)&part[((size_t)rc * 8 + b) * QKV_COLS + gcol] = acc[b];
}

// ---------------------------------------------------------------------------
// Kernel 2: reduce partials + bias + RoPE (pos = STARTPOS).  49152 threads.
__global__ __launch_bounds__(256) void qkv_reduce_rope_k(
    const float* __restrict__ part, const float* __restrict__ bq,
    const float* __restrict__ bk, const float* __restrict__ bv,
    float* __restrict__ qws, float* __restrict__ kws, float* __restrict__ vws) {
  int idx = blockIdx.x * 256 + threadIdx.x;
  int b = idx / QKV_COLS, col = idx % QKV_COLS;
  float s = 0.f;
#pragma unroll 8
  for (int rcc = 0; rcc < NRC; rcc++)
    s += part[((size_t)rcc * 8 + b) * QKV_COLS + col];
  float bias = (col < 4096) ? bq[col] : (col < 5120 ? bk[col - 4096] : bv[col - 5120]);
  s += bias;
  float outv = s;
  if (col < 5120) {  // q or k -> RoPE
    int dim = col & 127;
    int i2 = dim & ~1;
    float theta = powf(10000.f, -(float)i2 * (1.f / 128.f));
    float ang = (float)STARTPOS * theta;
    float c = cosf(ang), sn = sinf(ang);
    float other = __shfl_xor(s, 1);
    if ((col & 1) == 0) outv = s * c - other * sn;   // xr*cos - xi*sin
    else                outv = other * sn + s * c;   // xr*sin + xi*cos
  }
  if (col < 4096)       qws[b * 4096 + col] = outv;
  else if (col < 5120)  kws[b * 1024 + (col - 4096)] = outv;
  else                  vws[b * 1024 + (col - 5120)] = outv;
}

// ---------------------------------------------------------------------------
// Kernel 3: flash-decoding partials.  grid = 64 groups * 32 chunks of 128 pos,
// block = 256 thr = 4 waves.  Loads batched 4-deep in source for ILP;
// q staged in LDS (broadcast reads); one barrier pair.
__global__ __launch_bounds__(256, 4) void attn_partial_k(
    const float* __restrict__ q, const float* __restrict__ kws,
    const float* __restrict__ vws, const float* __restrict__ ck,
    const float* __restrict__ cv, float* __restrict__ pm,
    float* __restrict__ pl, float* __restrict__ pacc) {
  int bid = blockIdx.x;
  int chunk = bid & 31, grp = bid >> 5;
  int b = grp >> 3, hkv = grp & 7;
  int tid = threadIdx.x;
  int wv_ = tid >> 6, lane = tid & 63;

  __shared__ float sbuf[4][CPOS];
  __shared__ __align__(16) float qs[4][NDH];

  // stage q (4 heads x 128) into LDS
  for (int i = tid; i < 512; i += 256) {
    int h = i >> 7, d = i & 127;
    qs[h][d] = q[((size_t)b * NHQ + hkv * 4 + h) * NDH + d];
  }
  __syncthreads();

  int tchunk = chunk * CPOS;

  // ---- Phase 1: scores.  tid&127 = position, tid>>7 = head pair. ----
  {
    int pos = tid & 127;
    int hp = tid >> 7;          // 0 or 1
    int h0 = hp * 2;
    int t = tchunk + pos;
    const float* kr = (t == STARTPOS)
        ? (kws + ((size_t)b * NHKV + hkv) * NDH)
        : (ck + (((size_t)b * MAXSEQ + t) * NHKV + hkv) * NDH);
    const float4* kr4 = (const float4*)kr;
    const float4* qa4 = (const float4*)&qs[h0][0];
    const float4* qb4 = (const float4*)&qs[h0 + 1][0];
    float a0 = 0.f, a1 = 0.f;
#pragma unroll
    for (int j4 = 0; j4 < 32; j4 += 4) {
      float4 k0 = kr4[j4 + 0];
      float4 k1 = kr4[j4 + 1];
      float4 k2 = kr4[j4 + 2];
      float4 k3 = kr4[j4 + 3];
      float4 qa0 = qa4[j4 + 0], qa1 = qa4[j4 + 1], qa2 = qa4[j4 + 2], qa3 = qa4[j4 + 3];
      float4 qb0 = qb4[j4 + 0], qb1 = qb4[j4 + 1], qb2 = qb4[j4 + 2], qb3 = qb4[j4 + 3];
      a0 += DOT4(k0, qa0) + DOT4(k1, qa1) + DOT4(k2, qa2) + DOT4(k3, qa3);
      a1 += DOT4(k0, qb0) + DOT4(k1, qb1) + DOT4(k2, qb2) + DOT4(k3, qb3);
    }
    __syncthreads();  // qs no longer needed; also orders sbuf across waves below
    sbuf[h0][pos] = a0 * SCALE;
    sbuf[h0 + 1][pos] = a1 * SCALE;
  }
  __syncthreads();

  // ---- Phase 2: per-head softmax over the 128-pos chunk (wave = head). ----
  float e0 = sbuf[wv_][lane];
  float e1 = sbuf[wv_][lane + 64];
  float m = fmaxf(e0, e1);
#pragma unroll
  for (int off = 32; off; off >>= 1) m = fmaxf(m, __shfl_xor(m, off));
  float p0 = expf(e0 - m), p1 = expf(e1 - m);
  float l = p0 + p1;
#pragma unroll
  for (int off = 32; off; off >>= 1) l += __shfl_xor(l, off);
  sbuf[wv_][lane] = p0;
  sbuf[wv_][lane + 64] = p1;
  if (lane == 0) {
    pm[((size_t)grp * NCHUNK + chunk) * 4 + wv_] = m;
    pl[((size_t)grp * NCHUNK + chunk) * 4 + wv_] = l;
  }
  // PV only reads sbuf[wv_][*] (written by this wave) -> no barrier needed.

  // ---- Phase 3: PV.  half-wave per V row, lane covers a d-quad. ----
  int half = lane >> 5;
  int dq = (lane & 31) * 4;
  float4 acc = {0.f, 0.f, 0.f, 0.f};
  const float* vb = cv + (((size_t)b * MAXSEQ + tchunk) * NHKV + hkv) * NDH;
#pragma unroll 4
  for (int tt = 0; tt < CPOS; tt += 8) {
    float4 v0 = *(const float4*)(vb + (size_t)(tt + 0 + half) * 1024 + dq);
    float4 v1 = *(const float4*)(vb + (size_t)(tt + 2 + half) * 1024 + dq);
    float4 v2 = *(const float4*)(vb + (size_t)(tt + 4 + half) * 1024 + dq);
    float4 v3 = *(const float4*)(vb + (size_t)(tt + 6 + half) * 1024 + dq);
    float pp0 = sbuf[wv_][tt + 0 + half];
    float pp1 = sbuf[wv_][tt + 2 + half];
    float pp2 = sbuf[wv_][tt + 4 + half];
    float pp3 = sbuf[wv_][tt + 6 + half];
    acc.x += pp0 * v0.x + pp1 * v1.x + pp2 * v2.x + pp3 * v3.x;
    acc.y += pp0 * v0.y + pp1 * v1.y + pp2 * v2.y + pp3 * v3.y;
    acc.z += pp0 * v0.z + pp1 * v1.z + pp2 * v2.z + pp3 * v3.z;
    acc.w += pp0 * v0.w + pp1 * v1.w + pp2 * v2.w + pp3 * v3.w;
  }
  // Fix-up: the new token (t = STARTPOS = chunk 31, local row 127, half 1)
  // must use vws, not cache_v row 4095.
  if (chunk == 31 && half == 1) {
    float pp = sbuf[wv_][127];
    float4 vold = *(const float4*)(vb + (size_t)127 * 1024 + dq);
    float4 vnew = *(const float4*)(vws + ((size_t)b * NHKV + hkv) * NDH + dq);
    acc.x += pp * (vnew.x - vold.x);
    acc.y += pp * (vnew.y - vold.y);
    acc.z += pp * (vnew.z - vold.z);
    acc.w += pp * (vnew.w - vold.w);
  }
  acc.x += __shfl_xor(acc.x, 32);
  acc.y += __shfl_xor(acc.y, 32);
  acc.z += __shfl_xor(acc.z, 32);
  acc.w += __shfl_xor(acc.w, 32);
  if (half == 0)
    *(float4*)&pacc[(((size_t)grp * NCHUNK + chunk) * 4 + wv_) * NDH + dq] = acc;
}

// ---------------------------------------------------------------------------
// Kernel 4: combine 32 chunk partials per (b,hq).  grid 256, block 128.
__global__ __launch_bounds__(128) void attn_combine_k(
    const float* __restrict__ pm, const float* __restrict__ pl,
    const float* __restrict__ pacc, float* __restrict__ aout) {
  int bid = blockIdx.x;
  int b = bid >> 5, hq = bid & 31;
  int grp = b * 8 + (hq >> 2), r = hq & 3;
  int d = threadIdx.x;
  float mv[NCHUNK];
  float M = -1e30f;
#pragma unroll
  for (int c = 0; c < NCHUNK; c++) {
    mv[c] = pm[((size_t)grp * NCHUNK + c) * 4 + r];
    M = fmaxf(M, mv[c]);
  }
  float L = 0.f;
  float w[NCHUNK];
#pragma unroll
  for (int c = 0; c < NCHUNK; c++) {
    w[c] = expf(mv[c] - M);
    L += w[c] * pl[((size_t)grp * NCHUNK + c) * 4 + r];
  }
  float o = 0.f;
#pragma unroll
  for (int c = 0; c < NCHUNK; c++)
    o += w[c] * pacc[(((size_t)grp * NCHUNK + c) * 4 + r) * NDH + d];
  aout[(size_t)b * 4096 + hq * NDH + d] = o / L;
}

// ---------------------------------------------------------------------------
// Kernel 5: output projection partials. grid = 8 col-tiles * 64 row-chunks.
__global__ __launch_bounds__(256) void out_partial_k(
    const float* __restrict__ ain, const float* __restrict__ wo,
    float* __restrict__ part) {
  int bid = blockIdx.x;
  int ct = bid & 7, rc = bid >> 3;
  int tid = threadIdx.x;
  __shared__ __align__(16) float xs[RCHUNK][8];
  int rbase = rc * RCHUNK;
  for (int i = tid; i < RCHUNK * 8; i += 256) {
    int b = i >> 6, r = i & 63;
    xs[r][b] = ain[(size_t)b * 4096 + rbase + r];
  }
  __syncthreads();

  int col = ct * 512 + tid * 2;
  const float* wp = wo + (size_t)rbase * 4096 + col;
  float2 acc[8];
#pragma unroll
  for (int b = 0; b < 8; b++) { acc[b].x = 0.f; acc[b].y = 0.f; }
#pragma unroll 8
  for (int r = 0; r < RCHUNK; r++) {
    float2 w2 = *(const float2*)wp; wp += 4096;
    float4 xa = *(const float4*)&xs[r][0];
    float4 xb = *(const float4*)&xs[r][4];
    acc[0].x += xa.x * w2.x; acc[0].y += xa.x * w2.y;
    acc[1].x += xa.y * w2.x; acc[1].y += xa.y * w2.y;
    acc[2].x += xa.z * w2.x; acc[2].y += xa.z * w2.y;
    acc[3].x += xa.w * w2.x; acc[3].y += xa.w * w2.y;
    acc[4].x += xb.x * w2.x; acc[4].y += xb.x * w2.y;
    acc[5].x += xb.y * w2.x; acc[5].y += xb.y * w2.y;
    acc[6].x += xb.z * w2.x; acc[6].y += xb.z * w2.y;
    acc[7].x += xb.w * w2.x; acc[7].y += xb.w * w2.y;
  }
#pragma unroll
  for (int b = 0; b < 8; b++)
    *(float2*)&part[((size_t)rc * 8 + b) * 4096 + col] = acc[b];
}

// ---------------------------------------------------------------------------
// Kernel 6: reduce wo partials + bias -> d_out.  32768 threads.
__global__ __launch_bounds__(256) void out_reduce_k(
    const float* __restrict__ part, const float* __restrict__ bo,
    float* __restrict__ out) {
  int idx = blockIdx.x * 256 + threadIdx.x;
  int b = idx >> 12, col = idx & 4095;
  float s = bo[col];
#pragma unroll 8
  for (int rcc = 0; rcc < NRC; rcc++)
    s += part[((size_t)rcc * 8 + b) * 4096 + col];
  out[idx] = s;
  (void)b;
}

// ---------------------------------------------------------------------------
extern "C" void kernel_launch(void* const* d_in, const int* in_sizes, int n_in,
                              void* d_out, int out_size, void* d_ws, size_t ws_size,
                              hipStream_t stream) {
  const float* x       = (const float*)d_in[0];
  const float* wq      = (const float*)d_in[1];
  const float* bq      = (const float*)d_in[2];
  const float* wk      = (const float*)d_in[3];
  const float* bk      = (const float*)d_in[4];
  const float* wv      = (const float*)d_in[5];
  const float* bv      = (const float*)d_in[6];
  const float* wo      = (const float*)d_in[7];
  const float* bo      = (const float*)d_in[8];
  const float* cache_k = (const float*)d_in[9];
  const float* cache_v = (const float*)d_in[10];
  float* out = (float*)d_out;

  float* ws = (float*)d_ws;
  float* qkv_part = ws;                       // 64*8*6144 = 3,145,728 floats
  float* wo_part  = ws;                       // alias — reused after qkv consumed
  float* qws  = ws + 3145728;                 // 32768
  float* kws  = qws + 32768;                  // 8192
  float* vws  = kws + 8192;                   // 8192
  float* pm   = vws + 8192;                   // 8192  (64 grp * 32 chunk * 4)
  float* pl   = pm + 8192;                    // 8192
  float* pacc = pl + 8192;                    // 1,048,576
  float* aout = pacc + 1048576;               // 32768
  // total ~17.1 MB

  qkv_partial_k<<<768, 256, 0, stream>>>(x, wq, wk, wv, qkv_part);
  qkv_reduce_rope_k<<<192, 256, 0, stream>>>(qkv_part, bq, bk, bv, qws, kws, vws);
  attn_partial_k<<<2048, 256, 0, stream>>>(qws, kws, vws, cache_k, cache_v, pm, pl, pacc);
  attn_combine_k<<<256, 128, 0, stream>>>(pm, pl, pacc, aout);
  out_partial_k<<<512, 256, 0, stream>>>(aout, wo, wo_part);
  out_reduce_k<<<128, 256, 0, stream>>>(wo_part, bo, out);
}

// Round 4
// 131.033 us; speedup vs baseline: 1.0460x; 1.0460x over previous
//
#include <hip/hip_runtime.h>
#include <cmath>

#define NB 8
#define DIM 4096
#define NHQ 32
#define NHKV 8
#define NDH 128
#define MAXSEQ 4096
#define STARTPOS 4095
#define QKV_COLS 6144   // 4096 q + 1024 k + 1024 v
#define RCHUNK 64       // rows per split-K chunk
#define NRC 64          // 4096 / 64
#define SCALE 0.08838834764831845f  // 1/sqrt(128)
#define NCHUNK 32       // attn chunks
#define CPOS 128        // positions per attn chunk

#define DOT4(k, qq) ((k).x*(qq).x + (k).y*(qq).y + (k).z*(qq).z + (k).w*(qq).w)

// ---------------------------------------------------------------------------
// Kernel 1: QKV projection partials.  grid = 12 col-tiles * 64 row-chunks.
__global__ __launch_bounds__(256) void qkv_partial_k(
    const float* __restrict__ x, const float* __restrict__ wq,
    const float* __restrict__ wk, const float* __restrict__ wv,
    float* __restrict__ part) {
  int bid = blockIdx.x;
  int ct = bid % 12, rc = bid / 12;
  int tid = threadIdx.x;
  const float* W; int ldw; int colbase;
  int gcolbase = ct * 512;
  if (ct < 8)       { W = wq; ldw = NHQ * NDH;  colbase = gcolbase; }
  else if (ct < 10) { W = wk; ldw = NHKV * NDH; colbase = gcolbase - 4096; }
  else              { W = wv; ldw = NHKV * NDH; colbase = gcolbase - 5120; }

  __shared__ __align__(16) float xs[RCHUNK][8];
  int rbase = rc * RCHUNK;
  for (int i = tid; i < RCHUNK * 8; i += 256) {
    int b = i >> 6, r = i & 63;
    xs[r][b] = x[b * DIM + rbase + r];
  }
  __syncthreads();

  int col = colbase + tid * 2;
  const float* wp = W + (size_t)rbase * ldw + col;
  float2 acc[8];
#pragma unroll
  for (int b = 0; b < 8; b++) { acc[b].x = 0.f; acc[b].y = 0.f; }

#pragma unroll 8
  for (int r = 0; r < RCHUNK; r++) {
    float2 w2 = *(const float2*)wp; wp += ldw;
    float4 xa = *(const float4*)&xs[r][0];
    float4 xb = *(const float4*)&xs[r][4];
    acc[0].x += xa.x * w2.x; acc[0].y += xa.x * w2.y;
    acc[1].x += xa.y * w2.x; acc[1].y += xa.y * w2.y;
    acc[2].x += xa.z * w2.x; acc[2].y += xa.z * w2.y;
    acc[3].x += xa.w * w2.x; acc[3].y += xa.w * w2.y;
    acc[4].x += xb.x * w2.x; acc[4].y += xb.x * w2.y;
    acc[5].x += xb.y * w2.x; acc[5].y += xb.y * w2.y;
    acc[6].x += xb.z * w2.x; acc[6].y += xb.z * w2.y;
    acc[7].x += xb.w * w2.x; acc[7].y += xb.w * w2.y;
  }
  int gcol = gcolbase + tid * 2;
#pragma unroll
  for (int b = 0; b < 8; b++)
    *(float2*)&part[((size_t)rc * 8 + b) * QKV_COLS + gcol] = acc[b];
}

// ---------------------------------------------------------------------------
// Kernel 2: reduce partials + bias + RoPE (pos = STARTPOS).  49152 threads.
__global__ __launch_bounds__(256) void qkv_reduce_rope_k(
    const float* __restrict__ part, const float* __restrict__ bq,
    const float* __restrict__ bk, const float* __restrict__ bv,
    float* __restrict__ qws, float* __restrict__ kws, float* __restrict__ vws) {
  int idx = blockIdx.x * 256 + threadIdx.x;
  int b = idx / QKV_COLS, col = idx % QKV_COLS;
  float s = 0.f;
#pragma unroll 8
  for (int rcc = 0; rcc < NRC; rcc++)
    s += part[((size_t)rcc * 8 + b) * QKV_COLS + col];
  float bias = (col < 4096) ? bq[col] : (col < 5120 ? bk[col - 4096] : bv[col - 5120]);
  s += bias;
  float outv = s;
  if (col < 5120) {  // q or k -> RoPE
    int dim = col & 127;
    int i2 = dim & ~1;
    float theta = powf(10000.f, -(float)i2 * (1.f / 128.f));
    float ang = (float)STARTPOS * theta;
    float c = cosf(ang), sn = sinf(ang);
    float other = __shfl_xor(s, 1);
    if ((col & 1) == 0) outv = s * c - other * sn;   // xr*cos - xi*sin
    else                outv = other * sn + s * c;   // xr*sin + xi*cos
  }
  if (col < 4096)       qws[b * 4096 + col] = outv;
  else if (col < 5120)  kws[b * 1024 + (col - 4096)] = outv;
  else                  vws[b * 1024 + (col - 5120)] = outv;
}

// ---------------------------------------------------------------------------
// Kernel 3 (v3): flash-decoding partials, segment-coalesced K reads.
// grid = 64 groups * 32 chunks of 128 pos, block = 256 thr = 4 waves.
// Scores: 8 lanes per K row (lane&7 = 16B octant, lane>>3 = row) -> every
// load instruction covers 8 rows x 128B contiguous = 16 fully-used 64B lines.
// Partial dots reduced over the 8-lane group via shfl_xor(1,2,4).
// q fragments in registers (loaded once). K double-buffered across passes.
__global__ __launch_bounds__(256, 3) void attn_partial_k(
    const float* __restrict__ q, const float* __restrict__ kws,
    const float* __restrict__ vws, const float* __restrict__ ck,
    const float* __restrict__ cv, float* __restrict__ pm,
    float* __restrict__ pl, float* __restrict__ pacc) {
  int bid = blockIdx.x;
  int chunk = bid & 31, grp = bid >> 5;
  int b = grp >> 3, hkv = grp & 7;
  int tid = threadIdx.x;
  int wv_ = tid >> 6, lane = tid & 63;
  int l8 = lane & 7;    // 16B octant within a 128B j-slice
  int p8 = lane >> 3;   // row within a pass-group (0..7)

  __shared__ float sbuf[4][CPOS];

  int tchunk = chunk * CPOS;

  // ---- q fragments: qf[j][h] covers q[head h][j*32 + l8*4 .. +3] ----
  const float* qg = q + ((size_t)b * NHQ + hkv * 4) * NDH + l8 * 4;
  float4 qf[4][4];
#pragma unroll
  for (int j = 0; j < 4; j++)
#pragma unroll
    for (int h = 0; h < 4; h++)
      qf[j][h] = *(const float4*)(qg + h * NDH + j * 32);

  const size_t krow0 = (((size_t)b * MAXSEQ + tchunk) * NHKV + hkv) * NDH;
  const float* kwsrow = kws + ((size_t)b * NHKV + hkv) * NDH + l8 * 4;

  float accs[4][4];  // [pass][head], all indices compile-time after unroll
  float4 ka[4], kb[4];

#define KPTR(tl_) ((tchunk + (tl_)) == STARTPOS ? kwsrow \
    : (ck + krow0 + (size_t)(tl_) * (NHKV * NDH) + l8 * 4))
#define KLOAD(buf, tl_) { const float* kr_ = KPTR(tl_);                    \
    buf[0] = *(const float4*)(kr_);        buf[1] = *(const float4*)(kr_ + 32); \
    buf[2] = *(const float4*)(kr_ + 64);   buf[3] = *(const float4*)(kr_ + 96); }
#define KDOT(pp, buf) {                                                     \
    accs[pp][0] = DOT4(buf[0],qf[0][0])+DOT4(buf[1],qf[1][0])+DOT4(buf[2],qf[2][0])+DOT4(buf[3],qf[3][0]); \
    accs[pp][1] = DOT4(buf[0],qf[0][1])+DOT4(buf[1],qf[1][1])+DOT4(buf[2],qf[2][1])+DOT4(buf[3],qf[3][1]); \
    accs[pp][2] = DOT4(buf[0],qf[0][2])+DOT4(buf[1],qf[1][2])+DOT4(buf[2],qf[2][2])+DOT4(buf[3],qf[3][2]); \
    accs[pp][3] = DOT4(buf[0],qf[0][3])+DOT4(buf[1],qf[1][3])+DOT4(buf[2],qf[2][3])+DOT4(buf[3],qf[3][3]); }

  int pbase = wv_ * 32 + p8;
  KLOAD(ka, pbase + 0 * 8);
  KLOAD(kb, pbase + 1 * 8);
  KDOT(0, ka);
  KLOAD(ka, pbase + 2 * 8);
  KDOT(1, kb);
  KLOAD(kb, pbase + 3 * 8);
  KDOT(2, ka);
  KDOT(3, kb);
#undef KPTR
#undef KLOAD
#undef KDOT

  // reduce partial dots over the 8-lane octet; write scores to sbuf
#pragma unroll
  for (int p = 0; p < 4; p++) {
#pragma unroll
    for (int h = 0; h < 4; h++) {
      float a = accs[p][h];
      a += __shfl_xor(a, 1);
      a += __shfl_xor(a, 2);
      a += __shfl_xor(a, 4);
      accs[p][h] = a * SCALE;
    }
    int posl = wv_ * 32 + p * 8 + p8;
    float val = (l8 == 0) ? accs[p][0]
              : (l8 == 1) ? accs[p][1]
              : (l8 == 2) ? accs[p][2] : accs[p][3];
    if (l8 < 4) sbuf[l8][posl] = val;
  }
  __syncthreads();

  // ---- Phase 2: per-head softmax over the 128-pos chunk (wave = head). ----
  float e0 = sbuf[wv_][lane];
  float e1 = sbuf[wv_][lane + 64];
  float m = fmaxf(e0, e1);
#pragma unroll
  for (int off = 32; off; off >>= 1) m = fmaxf(m, __shfl_xor(m, off));
  float p0 = expf(e0 - m), p1 = expf(e1 - m);
  float l = p0 + p1;
#pragma unroll
  for (int off = 32; off; off >>= 1) l += __shfl_xor(l, off);
  sbuf[wv_][lane] = p0;
  sbuf[wv_][lane + 64] = p1;
  if (lane == 0) {
    pm[((size_t)grp * NCHUNK + chunk) * 4 + wv_] = m;
    pl[((size_t)grp * NCHUNK + chunk) * 4 + wv_] = l;
  }
  // PV only reads sbuf[wv_][*] (written by this wave) -> no barrier needed.

  // ---- Phase 3: PV.  half-wave per V row, lane covers a d-quad. ----
  int half = lane >> 5;
  int dq = (lane & 31) * 4;
  float4 acc = {0.f, 0.f, 0.f, 0.f};
  const float* vb = cv + (((size_t)b * MAXSEQ + tchunk) * NHKV + hkv) * NDH;
#pragma unroll 4
  for (int tt = 0; tt < CPOS; tt += 8) {
    float4 v0 = *(const float4*)(vb + (size_t)(tt + 0 + half) * 1024 + dq);
    float4 v1 = *(const float4*)(vb + (size_t)(tt + 2 + half) * 1024 + dq);
    float4 v2 = *(const float4*)(vb + (size_t)(tt + 4 + half) * 1024 + dq);
    float4 v3 = *(const float4*)(vb + (size_t)(tt + 6 + half) * 1024 + dq);
    float pp0 = sbuf[wv_][tt + 0 + half];
    float pp1 = sbuf[wv_][tt + 2 + half];
    float pp2 = sbuf[wv_][tt + 4 + half];
    float pp3 = sbuf[wv_][tt + 6 + half];
    acc.x += pp0 * v0.x + pp1 * v1.x + pp2 * v2.x + pp3 * v3.x;
    acc.y += pp0 * v0.y + pp1 * v1.y + pp2 * v2.y + pp3 * v3.y;
    acc.z += pp0 * v0.z + pp1 * v1.z + pp2 * v2.z + pp3 * v3.z;
    acc.w += pp0 * v0.w + pp1 * v1.w + pp2 * v2.w + pp3 * v3.w;
  }
  // Fix-up: the new token (t = STARTPOS = chunk 31, local row 127, half 1)
  // must use vws, not cache_v row 4095.
  if (chunk == 31 && half == 1) {
    float pp = sbuf[wv_][127];
    float4 vold = *(const float4*)(vb + (size_t)127 * 1024 + dq);
    float4 vnew = *(const float4*)(vws + ((size_t)b * NHKV + hkv) * NDH + dq);
    acc.x += pp * (vnew.x - vold.x);
    acc.y += pp * (vnew.y - vold.y);
    acc.z += pp * (vnew.z - vold.z);
    acc.w += pp * (vnew.w - vold.w);
  }
  acc.x += __shfl_xor(acc.x, 32);
  acc.y += __shfl_xor(acc.y, 32);
  acc.z += __shfl_xor(acc.z, 32);
  acc.w += __shfl_xor(acc.w, 32);
  if (half == 0)
    *(float4*)&pacc[(((size_t)grp * NCHUNK + chunk) * 4 + wv_) * NDH + dq] = acc;
}

// ---------------------------------------------------------------------------
// Kernel 4: combine 32 chunk partials per (b,hq).  grid 256, block 128.
__global__ __launch_bounds__(128) void attn_combine_k(
    const float* __restrict__ pm, const float* __restrict__ pl,
    const float* __restrict__ pacc, float* __restrict__ aout) {
  int bid = blockIdx.x;
  int b = bid >> 5, hq = bid & 31;
  int grp = b * 8 + (hq >> 2), r = hq & 3;
  int d = threadIdx.x;
  float mv[NCHUNK];
  float M = -1e30f;
#pragma unroll
  for (int c = 0; c < NCHUNK; c++) {
    mv[c] = pm[((size_t)grp * NCHUNK + c) * 4 + r];
    M = fmaxf(M, mv[c]);
  }
  float L = 0.f;
  float w[NCHUNK];
#pragma unroll
  for (int c = 0; c < NCHUNK; c++) {
    w[c] = expf(mv[c] - M);
    L += w[c] * pl[((size_t)grp * NCHUNK + c) * 4 + r];
  }
  float o = 0.f;
#pragma unroll
  for (int c = 0; c < NCHUNK; c++)
    o += w[c] * pacc[(((size_t)grp * NCHUNK + c) * 4 + r) * NDH + d];
  aout[(size_t)b * 4096 + hq * NDH + d] = o / L;
}

// ---------------------------------------------------------------------------
// Kernel 5: output projection partials. grid = 8 col-tiles * 64 row-chunks.
__global__ __launch_bounds__(256) void out_partial_k(
    const float* __restrict__ ain, const float* __restrict__ wo,
    float* __restrict__ part) {
  int bid = blockIdx.x;
  int ct = bid & 7, rc = bid >> 3;
  int tid = threadIdx.x;
  __shared__ __align__(16) float xs[RCHUNK][8];
  int rbase = rc * RCHUNK;
  for (int i = tid; i < RCHUNK * 8; i += 256) {
    int b = i >> 6, r = i & 63;
    xs[r][b] = ain[(size_t)b * 4096 + rbase + r];
  }
  __syncthreads();

  int col = ct * 512 + tid * 2;
  const float* wp = wo + (size_t)rbase * 4096 + col;
  float2 acc[8];
#pragma unroll
  for (int b = 0; b < 8; b++) { acc[b].x = 0.f; acc[b].y = 0.f; }
#pragma unroll 8
  for (int r = 0; r < RCHUNK; r++) {
    float2 w2 = *(const float2*)wp; wp += 4096;
    float4 xa = *(const float4*)&xs[r][0];
    float4 xb = *(const float4*)&xs[r][4];
    acc[0].x += xa.x * w2.x; acc[0].y += xa.x * w2.y;
    acc[1].x += xa.y * w2.x; acc[1].y += xa.y * w2.y;
    acc[2].x += xa.z * w2.x; acc[2].y += xa.z * w2.y;
    acc[3].x += xa.w * w2.x; acc[3].y += xa.w * w2.y;
    acc[4].x += xb.x * w2.x; acc[4].y += xb.x * w2.y;
    acc[5].x += xb.y * w2.x; acc[5].y += xb.y * w2.y;
    acc[6].x += xb.z * w2.x; acc[6].y += xb.z * w2.y;
    acc[7].x += xb.w * w2.x; acc[7].y += xb.w * w2.y;
  }
#pragma unroll
  for (int b = 0; b < 8; b++)
    *(float2*)&part[((size_t)rc * 8 + b) * 4096 + col] = acc[b];
}

// ---------------------------------------------------------------------------
// Kernel 6: reduce wo partials + bias -> d_out.  32768 threads.
__global__ __launch_bounds__(256) void out_reduce_k(
    const float* __restrict__ part, const float* __restrict__ bo,
    float* __restrict__ out) {
  int idx = blockIdx.x * 256 + threadIdx.x;
  int b = idx >> 12, col = idx & 4095;
  float s = bo[col];
#pragma unroll 8
  for (int rcc = 0; rcc < NRC; rcc++)
    s += part[((size_t)rcc * 8 + b) * 4096 + col];
  out[idx] = s;
  (void)b;
}

// ---------------------------------------------------------------------------
extern "C" void kernel_launch(void* const* d_in, const int* in_sizes, int n_in,
                              void* d_out, int out_size, void* d_ws, size_t ws_size,
                              hipStream_t stream) {
  const float* x       = (const float*)d_in[0];
  const float* wq      = (const float*)d_in[1];
  const float* bq      = (const float*)d_in[2];
  const float* wk      = (const float*)d_in[3];
  const float* bk      = (const float*)d_in[4];
  const float* wv      = (const float*)d_in[5];
  const float* bv      = (const float*)d_in[6];
  const float* wo      = (const float*)d_in[7];
  const float* bo      = (const float*)d_in[8];
  const float* cache_k = (const float*)d_in[9];
  const float* cache_v = (const float*)d_in[10];
  float* out = (float*)d_out;

  float* ws = (float*)d_ws;
  float* qkv_part = ws;                       // 64*8*6144 = 3,145,728 floats
  float* wo_part  = ws;                       // alias — reused after qkv consumed
  float* qws  = ws + 3145728;                 // 32768
  float* kws  = qws + 32768;                  // 8192
  float* vws  = kws + 8192;                   // 8192
  float* pm   = vws + 8192;                   // 8192  (64 grp * 32 chunk * 4)
  float* pl   = pm + 8192;                    // 8192
  float* pacc = pl + 8192;                    // 1,048,576
  float* aout = pacc + 1048576;               // 32768
  // total ~17.1 MB

  qkv_partial_k<<<768, 256, 0, stream>>>(x, wq, wk, wv, qkv_part);
  qkv_reduce_rope_k<<<192, 256, 0, stream>>>(qkv_part, bq, bk, bv, qws, kws, vws);
  attn_partial_k<<<2048, 256, 0, stream>>>(qws, kws, vws, cache_k, cache_v, pm, pl, pacc);
  attn_combine_k<<<256, 128, 0, stream>>>(pm, pl, pacc, aout);
  out_partial_k<<<512, 256, 0, stream>>>(aout, wo, wo_part);
  out_reduce_k<<<128, 256, 0, stream>>>(wo_part, bo, out);
}

// Round 6
// 118.626 us; speedup vs baseline: 1.1554x; 1.1046x over previous
//
#include <hip/hip_runtime.h>
#include <cmath>

#define NB 8
#define DIM 4096
#define NHQ 32
#define NHKV 8
#define NDH 128
#define MAXSEQ 4096
#define STARTPOS 4095
#define QKV_COLS 6144   // 4096 q + 1024 k + 1024 v
#define RCHUNK 64       // rows per split-K chunk
#define NRC 64          // 4096 / 64
#define SCALE 0.08838834764831845f  // 1/sqrt(128)

#define DOT4(k, qq) ((k).x*(qq).x + (k).y*(qq).y + (k).z*(qq).z + (k).w*(qq).w)

// ---------------------------------------------------------------------------
// Kernel 1: QKV projection partials.  grid = 12 col-tiles * 64 row-chunks.
__global__ __launch_bounds__(256) void qkv_partial_k(
    const float* __restrict__ x, const float* __restrict__ wq,
    const float* __restrict__ wk, const float* __restrict__ wv,
    float* __restrict__ part) {
  int bid = blockIdx.x;
  int ct = bid % 12, rc = bid / 12;
  int tid = threadIdx.x;
  const float* W; int ldw; int colbase;
  int gcolbase = ct * 512;
  if (ct < 8)       { W = wq; ldw = NHQ * NDH;  colbase = gcolbase; }
  else if (ct < 10) { W = wk; ldw = NHKV * NDH; colbase = gcolbase - 4096; }
  else              { W = wv; ldw = NHKV * NDH; colbase = gcolbase - 5120; }

  __shared__ __align__(16) float xs[RCHUNK][8];
  int rbase = rc * RCHUNK;
  for (int i = tid; i < RCHUNK * 8; i += 256) {
    int b = i >> 6, r = i & 63;
    xs[r][b] = x[b * DIM + rbase + r];
  }
  __syncthreads();

  int col = colbase + tid * 2;
  const float* wp = W + (size_t)rbase * ldw + col;
  float2 acc[8];
#pragma unroll
  for (int b = 0; b < 8; b++) { acc[b].x = 0.f; acc[b].y = 0.f; }

#pragma unroll 8
  for (int r = 0; r < RCHUNK; r++) {
    float2 w2 = *(const float2*)wp; wp += ldw;
    float4 xa = *(const float4*)&xs[r][0];
    float4 xb = *(const float4*)&xs[r][4];
    acc[0].x += xa.x * w2.x; acc[0].y += xa.x * w2.y;
    acc[1].x += xa.y * w2.x; acc[1].y += xa.y * w2.y;
    acc[2].x += xa.z * w2.x; acc[2].y += xa.z * w2.y;
    acc[3].x += xa.w * w2.x; acc[3].y += xa.w * w2.y;
    acc[4].x += xb.x * w2.x; acc[4].y += xb.x * w2.y;
    acc[5].x += xb.y * w2.x; acc[5].y += xb.y * w2.y;
    acc[6].x += xb.z * w2.x; acc[6].y += xb.z * w2.y;
    acc[7].x += xb.w * w2.x; acc[7].y += xb.w * w2.y;
  }
  int gcol = gcolbase + tid * 2;
#pragma unroll
  for (int b = 0; b < 8; b++)
    *(float2*)&part[((size_t)rc * 8 + b) * QKV_COLS + gcol] = acc[b];
}

// ---------------------------------------------------------------------------
// Kernel 2: reduce partials + bias + RoPE (pos = STARTPOS).  49152 threads.
__global__ __launch_bounds__(256) void qkv_reduce_rope_k(
    const float* __restrict__ part, const float* __restrict__ bq,
    const float* __restrict__ bk, const float* __restrict__ bv,
    float* __restrict__ qws, float* __restrict__ kws, float* __restrict__ vws) {
  int idx = blockIdx.x * 256 + threadIdx.x;
  int b = idx / QKV_COLS, col = idx % QKV_COLS;
  float s = 0.f;
#pragma unroll 8
  for (int rcc = 0; rcc < NRC; rcc++)
    s += part[((size_t)rcc * 8 + b) * QKV_COLS + col];
  float bias = (col < 4096) ? bq[col] : (col < 5120 ? bk[col - 4096] : bv[col - 5120]);
  s += bias;
  float outv = s;
  if (col < 5120) {  // q or k -> RoPE
    int dim = col & 127;
    int i2 = dim & ~1;
    float theta = powf(10000.f, -(float)i2 * (1.f / 128.f));
    float ang = (float)STARTPOS * theta;
    float c = cosf(ang), sn = sinf(ang);
    float other = __shfl_xor(s, 1);
    if ((col & 1) == 0) outv = s * c - other * sn;   // xr*cos - xi*sin
    else                outv = other * sn + s * c;   // xr*sin + xi*cos
  }
  if (col < 4096)       qws[b * 4096 + col] = outv;
  else if (col < 5120)  kws[b * 1024 + (col - 4096)] = outv;
  else                  vws[b * 1024 + (col - 5120)] = outv;
}

// ---------------------------------------------------------------------------
// Kernel 3: scores.  grid = 8 b * 128 chunks of 32 t.  256 thr = 4 waves.
// Block reads CONTIGUOUS 128 KB of K (all 8 hkv per t).  Octet p8 <-> hkv=p8.
// Writes S[b][t][hq] (coalesced 128B/iter) + per-block online-softmax partials.
__global__ __launch_bounds__(256, 3) void scores_k(
    const float* __restrict__ qws, const float* __restrict__ kws,
    const float* __restrict__ ck, float* __restrict__ S,
    float* __restrict__ pmx, float* __restrict__ psm) {
  int bid = blockIdx.x;
  int chunk = bid & 127, b = bid >> 7;
  int tid = threadIdx.x;
  int w = tid >> 6, lane = tid & 63;
  int p8 = lane >> 3, l8 = lane & 7;

  // q fragments: heads p8*4..+3, slice floats l8*4 + j*32
  float4 qf[4][4];
  const float* qb = qws + ((size_t)b * NHQ + p8 * 4) * NDH + l8 * 4;
#pragma unroll
  for (int h = 0; h < 4; h++)
#pragma unroll
    for (int j = 0; j < 4; j++)
      qf[h][j] = *(const float4*)(qb + h * NDH + j * 32);

  const float* kbase = ck + (size_t)(b * MAXSEQ + chunk * 32) * (NHKV * NDH);
  const float* kwsrow = kws + ((size_t)b * NHKV + p8) * NDH + l8 * 4;

  float m_run = -1e30f, s_run = 0.f;   // online softmax over this lane's 8 t's
  float4 ka[4], kb_[4];

#define SLOAD(buf, i_) { \
    const float* kr_; \
    if (chunk * 32 + (i_) * 4 + w == STARTPOS) kr_ = kwsrow; \
    else kr_ = kbase + (size_t)((i_) * 32 + w * 8 + p8) * NDH + l8 * 4; \
    buf[0] = *(const float4*)(kr_);       buf[1] = *(const float4*)(kr_ + 32); \
    buf[2] = *(const float4*)(kr_ + 64);  buf[3] = *(const float4*)(kr_ + 96); }

#define SPROC(buf, i_) { \
    float a0 = DOT4(buf[0],qf[0][0])+DOT4(buf[1],qf[0][1])+DOT4(buf[2],qf[0][2])+DOT4(buf[3],qf[0][3]); \
    float a1 = DOT4(buf[0],qf[1][0])+DOT4(buf[1],qf[1][1])+DOT4(buf[2],qf[1][2])+DOT4(buf[3],qf[1][3]); \
    float a2 = DOT4(buf[0],qf[2][0])+DOT4(buf[1],qf[2][1])+DOT4(buf[2],qf[2][2])+DOT4(buf[3],qf[2][3]); \
    float a3 = DOT4(buf[0],qf[3][0])+DOT4(buf[1],qf[3][1])+DOT4(buf[2],qf[3][2])+DOT4(buf[3],qf[3][3]); \
    a0 += __shfl_xor(a0,1); a0 += __shfl_xor(a0,2); a0 += __shfl_xor(a0,4); \
    a1 += __shfl_xor(a1,1); a1 += __shfl_xor(a1,2); a1 += __shfl_xor(a1,4); \
    a2 += __shfl_xor(a2,1); a2 += __shfl_xor(a2,2); a2 += __shfl_xor(a2,4); \
    a3 += __shfl_xor(a3,1); a3 += __shfl_xor(a3,2); a3 += __shfl_xor(a3,4); \
    float v_ = ((l8==0)?a0:(l8==1)?a1:(l8==2)?a2:a3) * SCALE; \
    int tg_ = chunk * 32 + (i_) * 4 + w; \
    if (l8 < 4) S[((size_t)b * MAXSEQ + tg_) * NHQ + p8 * 4 + l8] = v_; \
    float mn_ = fmaxf(m_run, v_); \
    s_run = s_run * expf(m_run - mn_) + expf(v_ - mn_); \
    m_run = mn_; }

  SLOAD(ka, 0); SLOAD(kb_, 1);
  SPROC(ka, 0); SLOAD(ka, 2);
  SPROC(kb_, 1); SLOAD(kb_, 3);
  SPROC(ka, 2); SLOAD(ka, 4);
  SPROC(kb_, 3); SLOAD(kb_, 5);
  SPROC(ka, 4); SLOAD(ka, 6);
  SPROC(kb_, 5); SLOAD(kb_, 7);
  SPROC(ka, 6);
  SPROC(kb_, 7);
#undef SLOAD
#undef SPROC

  // cross-wave combine of (m,l) partials -> per-block per-head partials
  __shared__ float red[4][NHQ][2];
  if (l8 < 4) { red[w][p8 * 4 + l8][0] = m_run; red[w][p8 * 4 + l8][1] = s_run; }
  __syncthreads();
  if (tid < NHQ) {
    float M = red[0][tid][0], L = red[0][tid][1];
#pragma unroll
    for (int ww = 1; ww < 4; ww++) {
      float m2 = red[ww][tid][0], l2 = red[ww][tid][1];
      float Mn = fmaxf(M, m2);
      L = L * expf(M - Mn) + l2 * expf(m2 - Mn);
      M = Mn;
    }
    pmx[((size_t)b * 128 + chunk) * NHQ + tid] = M;
    psm[((size_t)b * 128 + chunk) * NHQ + tid] = L;
  }
}

// ---------------------------------------------------------------------------
// Kernel 4: PV.  grid = 8 b * 64 chunks of 64 t.  256 thr = 4 waves.
// Combines (m,l) partials, stages normalized P in LDS, then streams
// CONTIGUOUS 256 KB of V; register accumulators.  Each wave covers the t's
// with t_local%4==w; waves 1-3 dump acc to LDS, wave 0 reduces and is the
// SOLE pacc writer (fixes the round-5 cross-wave race).
__global__ __launch_bounds__(256, 2) void pv_k(
    const float* __restrict__ S, const float* __restrict__ pmx,
    const float* __restrict__ psm, const float* __restrict__ vws,
    const float* __restrict__ cv, float* __restrict__ pacc) {
  int bid = blockIdx.x;
  int chunk = bid & 63, b = bid >> 6;
  int tid = threadIdx.x;
  int w = tid >> 6, lane = tid & 63;
  int p8 = lane >> 3, l8 = lane & 7;

  __shared__ float ml[NHQ][2];
  __shared__ float pbuf[NHQ][65];
  __shared__ float red2[8][NHQ][2];
  __shared__ __align__(16) float axl[3][64][68];  // waves 1-3 acc dump (padded)

  // combine m/l over the 128 score-chunks (redundant per block; tiny)
  {
    int hq = tid & 31, part = tid >> 5;
    float M = -1e30f, L = 0.f;
    for (int c = part; c < 128; c += 8) {
      float m2 = pmx[((size_t)b * 128 + c) * NHQ + hq];
      float l2 = psm[((size_t)b * 128 + c) * NHQ + hq];
      float Mn = fmaxf(M, m2);
      L = L * expf(M - Mn) + l2 * expf(m2 - Mn);
      M = Mn;
    }
    red2[part][hq][0] = M; red2[part][hq][1] = L;
    __syncthreads();
    if (tid < NHQ) {
      float M0 = red2[0][tid][0], L0 = red2[0][tid][1];
#pragma unroll
      for (int pp = 1; pp < 8; pp++) {
        float m2 = red2[pp][tid][0], l2 = red2[pp][tid][1];
        float Mn = fmaxf(M0, m2);
        L0 = L0 * expf(M0 - Mn) + l2 * expf(m2 - Mn);
        M0 = Mn;
      }
      ml[tid][0] = M0; ml[tid][1] = 1.0f / L0;
    }
    __syncthreads();
  }

  // stage normalized P for this block's 64 t's
  for (int idx = tid; idx < 64 * NHQ; idx += 256) {
    int tl = idx >> 5, hq = idx & 31;
    float s = S[((size_t)b * MAXSEQ + chunk * 64 + tl) * NHQ + hq];
    pbuf[hq][tl] = expf(s - ml[hq][0]) * ml[hq][1];
  }
  __syncthreads();

  const float* vbase = cv + (size_t)(b * MAXSEQ + chunk * 64) * (NHKV * NDH);
  const float* vwsrow = vws + ((size_t)b * NHKV + p8) * NDH + l8 * 4;

  float4 acc[4][4];  // [h][j]
#pragma unroll
  for (int h = 0; h < 4; h++)
#pragma unroll
    for (int j = 0; j < 4; j++) acc[h][j] = (float4){0.f, 0.f, 0.f, 0.f};

  float4 va[4], vb_[4];

#define VLOAD(buf, i_) { \
    const float* vr_; \
    if (chunk * 64 + (i_) * 4 + w == STARTPOS) vr_ = vwsrow; \
    else vr_ = vbase + (size_t)((i_) * 32 + w * 8 + p8) * NDH + l8 * 4; \
    buf[0] = *(const float4*)(vr_);       buf[1] = *(const float4*)(vr_ + 32); \
    buf[2] = *(const float4*)(vr_ + 64);  buf[3] = *(const float4*)(vr_ + 96); }

#define VPROC(buf, i_) { \
    int tl_ = (i_) * 4 + w; \
    float pp0 = pbuf[p8 * 4 + 0][tl_]; \
    float pp1 = pbuf[p8 * 4 + 1][tl_]; \
    float pp2 = pbuf[p8 * 4 + 2][tl_]; \
    float pp3 = pbuf[p8 * 4 + 3][tl_]; \
    _Pragma("unroll") \
    for (int j = 0; j < 4; j++) { \
      acc[0][j].x += pp0 * buf[j].x; acc[0][j].y += pp0 * buf[j].y; \
      acc[0][j].z += pp0 * buf[j].z; acc[0][j].w += pp0 * buf[j].w; \
      acc[1][j].x += pp1 * buf[j].x; acc[1][j].y += pp1 * buf[j].y; \
      acc[1][j].z += pp1 * buf[j].z; acc[1][j].w += pp1 * buf[j].w; \
      acc[2][j].x += pp2 * buf[j].x; acc[2][j].y += pp2 * buf[j].y; \
      acc[2][j].z += pp2 * buf[j].z; acc[2][j].w += pp2 * buf[j].w; \
      acc[3][j].x += pp3 * buf[j].x; acc[3][j].y += pp3 * buf[j].y; \
      acc[3][j].z += pp3 * buf[j].z; acc[3][j].w += pp3 * buf[j].w; } }

  VLOAD(va, 0); VLOAD(vb_, 1);
  VPROC(va, 0);  VLOAD(va, 2);
  VPROC(vb_, 1); VLOAD(vb_, 3);
  VPROC(va, 2);  VLOAD(va, 4);
  VPROC(vb_, 3); VLOAD(vb_, 5);
  VPROC(va, 4);  VLOAD(va, 6);
  VPROC(vb_, 5); VLOAD(vb_, 7);
  VPROC(va, 6);  VLOAD(va, 8);
  VPROC(vb_, 7); VLOAD(vb_, 9);
  VPROC(va, 8);  VLOAD(va, 10);
  VPROC(vb_, 9); VLOAD(vb_, 11);
  VPROC(va, 10); VLOAD(va, 12);
  VPROC(vb_, 11); VLOAD(vb_, 13);
  VPROC(va, 12); VLOAD(va, 14);
  VPROC(vb_, 13); VLOAD(vb_, 15);
  VPROC(va, 14);
  VPROC(vb_, 15);
#undef VLOAD
#undef VPROC

  // ---- cross-wave reduction: waves 1-3 -> LDS, wave 0 sums & writes. ----
  if (w > 0) {
#pragma unroll
    for (int h = 0; h < 4; h++)
#pragma unroll
      for (int j = 0; j < 4; j++)
        *(float4*)&axl[w - 1][lane][h * 16 + j * 4] = acc[h][j];
  }
  __syncthreads();
  if (w == 0) {
#pragma unroll
    for (int ww = 0; ww < 3; ww++)
#pragma unroll
      for (int h = 0; h < 4; h++)
#pragma unroll
        for (int j = 0; j < 4; j++) {
          float4 t4 = *(const float4*)&axl[ww][lane][h * 16 + j * 4];
          acc[h][j].x += t4.x; acc[h][j].y += t4.y;
          acc[h][j].z += t4.z; acc[h][j].w += t4.w;
        }
    float* pb = pacc + (((size_t)chunk * NB + b) * NHQ + p8 * 4) * NDH + l8 * 4;
#pragma unroll
    for (int h = 0; h < 4; h++)
#pragma unroll
      for (int j = 0; j < 4; j++)
        *(float4*)(pb + h * NDH + j * 32) = acc[h][j];
  }
}

// ---------------------------------------------------------------------------
// Kernel 5: reduce PV partials over 64 chunks -> aout.  grid 128 * 256.
__global__ __launch_bounds__(256) void pv_reduce_k(
    const float* __restrict__ pacc, float* __restrict__ aout) {
  int idx = blockIdx.x * 256 + threadIdx.x;
  int b = idx >> 12, rest = idx & 4095;
  float s = 0.f;
#pragma unroll 8
  for (int c = 0; c < 64; c++)
    s += pacc[((size_t)c * NB + b) * 4096 + rest];
  aout[idx] = s;
}

// ---------------------------------------------------------------------------
// Kernel 6: output projection partials. grid = 8 col-tiles * 64 row-chunks.
__global__ __launch_bounds__(256) void out_partial_k(
    const float* __restrict__ ain, const float* __restrict__ wo,
    float* __restrict__ part) {
  int bid = blockIdx.x;
  int ct = bid & 7, rc = bid >> 3;
  int tid = threadIdx.x;
  __shared__ __align__(16) float xs[RCHUNK][8];
  int rbase = rc * RCHUNK;
  for (int i = tid; i < RCHUNK * 8; i += 256) {
    int b = i >> 6, r = i & 63;
    xs[r][b] = ain[(size_t)b * 4096 + rbase + r];
  }
  __syncthreads();

  int col = ct * 512 + tid * 2;
  const float* wp = wo + (size_t)rbase * 4096 + col;
  float2 acc[8];
#pragma unroll
  for (int b = 0; b < 8; b++) { acc[b].x = 0.f; acc[b].y = 0.f; }
#pragma unroll 8
  for (int r = 0; r < RCHUNK; r++) {
    float2 w2 = *(const float2*)wp; wp += 4096;
    float4 xa = *(const float4*)&xs[r][0];
    float4 xb = *(const float4*)&xs[r][4];
    acc[0].x += xa.x * w2.x; acc[0].y += xa.x * w2.y;
    acc[1].x += xa.y * w2.x; acc[1].y += xa.y * w2.y;
    acc[2].x += xa.z * w2.x; acc[2].y += xa.z * w2.y;
    acc[3].x += xa.w * w2.x; acc[3].y += xa.w * w2.y;
    acc[4].x += xb.x * w2.x; acc[4].y += xb.x * w2.y;
    acc[5].x += xb.y * w2.x; acc[5].y += xb.y * w2.y;
    acc[6].x += xb.z * w2.x; acc[6].y += xb.z * w2.y;
    acc[7].x += xb.w * w2.x; acc[7].y += xb.w * w2.y;
  }
#pragma unroll
  for (int b = 0; b < 8; b++)
    *(float2*)&part[((size_t)rc * 8 + b) * 4096 + col] = acc[b];
}

// ---------------------------------------------------------------------------
// Kernel 7: reduce wo partials + bias -> d_out.  32768 threads.
__global__ __launch_bounds__(256) void out_reduce_k(
    const float* __restrict__ part, const float* __restrict__ bo,
    float* __restrict__ out) {
  int idx = blockIdx.x * 256 + threadIdx.x;
  int b = idx >> 12, col = idx & 4095;
  float s = bo[col];
#pragma unroll 8
  for (int rcc = 0; rcc < NRC; rcc++)
    s += part[((size_t)rcc * 8 + b) * 4096 + col];
  out[idx] = s;
  (void)b;
}

// ---------------------------------------------------------------------------
extern "C" void kernel_launch(void* const* d_in, const int* in_sizes, int n_in,
                              void* d_out, int out_size, void* d_ws, size_t ws_size,
                              hipStream_t stream) {
  const float* x       = (const float*)d_in[0];
  const float* wq      = (const float*)d_in[1];
  const float* bq      = (const float*)d_in[2];
  const float* wk      = (const float*)d_in[3];
  const float* bk      = (const float*)d_in[4];
  const float* wv      = (const float*)d_in[5];
  const float* bv      = (const float*)d_in[6];
  const float* wo      = (const float*)d_in[7];
  const float* bo      = (const float*)d_in[8];
  const float* cache_k = (const float*)d_in[9];
  const float* cache_v = (const float*)d_in[10];
  float* out = (float*)d_out;

  float* ws = (float*)d_ws;
  // region0 [0, 3,145,728): qkv_part -> pacc(2,097,152) -> wo_part(2,097,152)
  //   pmx/psm live at region0+2,097,152 (written k3, dead before out_partial)
  float* qkv_part = ws;
  float* pacc     = ws;
  float* wo_part  = ws;
  float* pmx  = ws + 2097152;                 // 32768
  float* psm  = ws + 2097152 + 32768;         // 32768
  float* S    = ws + 3145728;                 // 1,048,576
  float* qws  = ws + 4194304;                 // 32768
  float* kws  = ws + 4227072;                 // 8192
  float* vws  = ws + 4235264;                 // 8192
  float* aout = ws + 4243456;                 // 32768 -> end 4,276,224 (17.10 MB)

  qkv_partial_k<<<768, 256, 0, stream>>>(x, wq, wk, wv, qkv_part);
  qkv_reduce_rope_k<<<192, 256, 0, stream>>>(qkv_part, bq, bk, bv, qws, kws, vws);
  scores_k<<<1024, 256, 0, stream>>>(qws, kws, cache_k, S, pmx, psm);
  pv_k<<<512, 256, 0, stream>>>(S, pmx, psm, vws, cache_v, pacc);
  pv_reduce_k<<<128, 256, 0, stream>>>(pacc, aout);
  out_partial_k<<<512, 256, 0, stream>>>(aout, wo, wo_part);
  out_reduce_k<<<128, 256, 0, stream>>>(wo_part, bo, out);
}